// Round 3
// baseline (4106.335 us; speedup 1.0000x reference)
//
#include <hip/hip_runtime.h>
#include <math.h>

#define N_NODES 100000
#define CDIM 128
#define E_EDGES 500000
#define NEG_SLOPE 0.2f

typedef __attribute__((ext_vector_type(8))) short short8;           // 8 bf16 (MFMA frag)
typedef __attribute__((ext_vector_type(8))) unsigned short ushort8; // 8 bf16 (loads)
typedef __attribute__((ext_vector_type(4))) float f32x4;

static __device__ __forceinline__ float bf2f(unsigned short u) {
    unsigned int t = ((unsigned int)u) << 16;
    return __builtin_bit_cast(float, t);
}
static __device__ __forceinline__ unsigned short f2bf(float f) {
    unsigned int u = __builtin_bit_cast(unsigned int, f);
    unsigned int r = (u + 0x7FFFu + ((u >> 16) & 1u)) >> 16;   // RNE
    return (unsigned short)r;
}
static __device__ __forceinline__ int clampi(int v, int hi) {
    return v < 0 ? 0 : (v >= hi ? hi - 1 : v);
}

// ---- split one fp32 128x128 W into transposed bf16 hi/lo: WTh[j,k]+WTl[j,k] ≈ W[k,j]
__global__ void split_w(const float* __restrict__ W,
                        unsigned short* __restrict__ WTh,
                        unsigned short* __restrict__ WTl) {
    int idx = blockIdx.x * 256 + threadIdx.x;   // 0..16383
    int j = idx >> 7, k = idx & 127;
    float v = W[k * 128 + j];
    unsigned short h = f2bf(v);
    float r = v - bf2f(h);
    WTh[idx] = h;
    WTl[idx] = f2bf(r);
}

// ---- fused 3-way projection: A=bf16(X@Wl), B=bf16(X@Wr), R=fp32(X@Wres + bias)
// X fp32 [n,128]. WT base holds 3 mats x (hi,lo) transposed bf16, each 16384.
// Split-bf16 GEMM: X@W = Xh@Wh + Xh@Wl + Xl@Wh  (~fp32 accurate).
// block=256 (4 waves); block tile 64 rows; wave tile 16 rows x 128 cols.
// In-place safe: each block reads only rows it writes, stores after its reads.
__global__ __launch_bounds__(256)
void proj3(const float* __restrict__ X,
           const unsigned short* __restrict__ WT,
           const float* __restrict__ bias,
           unsigned short* __restrict__ A,
           unsigned short* __restrict__ B,
           float* __restrict__ R, int n_rows) {
    const int lane = threadIdx.x & 63;
    const int wave = threadIdx.x >> 6;
    const int m    = lane & 15;
    const int quad = lane >> 4;
    const int row0 = blockIdx.x * 64 + wave * 16;

    int arow = row0 + m;
    if (arow >= n_rows) arow = n_rows - 1;   // clamp loads; stores guarded

    const unsigned short* Wh[3] = {WT, WT + 2 * 16384, WT + 4 * 16384};
    const unsigned short* Wl[3] = {WT + 16384, WT + 3 * 16384, WT + 5 * 16384};

    f32x4 acc[3][8];
#pragma unroll
    for (int mi = 0; mi < 3; ++mi)
#pragma unroll
        for (int t = 0; t < 8; ++t) acc[mi][t] = (f32x4)0.0f;

#pragma unroll
    for (int kk = 0; kk < 4; ++kk) {
        const int kb = kk * 32 + quad * 8;
        const float* xp = X + (size_t)arow * CDIM + kb;
        f32x4 x0 = *(const f32x4*)xp;
        f32x4 x1 = *(const f32x4*)(xp + 4);
        short8 ah, al;
#pragma unroll
        for (int j = 0; j < 4; ++j) {
            unsigned short h0 = f2bf(x0[j]);
            ah[j] = (short)h0;
            al[j] = (short)f2bf(x0[j] - bf2f(h0));
            unsigned short h1 = f2bf(x1[j]);
            ah[4 + j] = (short)h1;
            al[4 + j] = (short)f2bf(x1[j] - bf2f(h1));
        }
#pragma unroll
        for (int t = 0; t < 8; ++t) {
            const size_t wo = (size_t)(t * 16 + m) * CDIM + kb;
#pragma unroll
            for (int mi = 0; mi < 3; ++mi) {
                short8 bh = *(const short8*)(Wh[mi] + wo);
                short8 bl = *(const short8*)(Wl[mi] + wo);
                acc[mi][t] = __builtin_amdgcn_mfma_f32_16x16x32_bf16(ah, bl, acc[mi][t], 0, 0, 0);
                acc[mi][t] = __builtin_amdgcn_mfma_f32_16x16x32_bf16(al, bh, acc[mi][t], 0, 0, 0);
                acc[mi][t] = __builtin_amdgcn_mfma_f32_16x16x32_bf16(ah, bh, acc[mi][t], 0, 0, 0);
            }
        }
    }

#pragma unroll
    for (int t = 0; t < 8; ++t) {
        const int col = t * 16 + m;
        const float bv = bias[col];
#pragma unroll
        for (int r = 0; r < 4; ++r) {
            const int row = row0 + quad * 4 + r;
            if (row < n_rows) {
                const size_t o = (size_t)row * CDIM + col;
                A[o] = f2bf(acc[0][t][r]);
                B[o] = f2bf(acc[1][t][r]);
                R[o] = acc[2][t][r] + bv;
            }
        }
    }
}

// ---- edge pass 1: e = dot(leaky_relu(xl[src]+xr[dst]), att); ee=exp(e); denom[dst]+=ee
// 16 lanes/edge, 8 channels/lane. A,B bf16; att fp32.
__global__ __launch_bounds__(256)
void edge_logits(const int* __restrict__ src, const int* __restrict__ dst,
                 const unsigned short* __restrict__ A,
                 const unsigned short* __restrict__ B,
                 const float* __restrict__ att,
                 float* __restrict__ ee, float* __restrict__ denom, int n_edges) {
    int t = blockIdx.x * 256 + threadIdx.x;
    int eid = t >> 4;
    int sub = t & 15;
    if (eid >= n_edges) return;
    int s = clampi(src[eid], N_NODES);
    int d = clampi(dst[eid], N_NODES);
    int c0 = sub * 8;

    ushort8 ua = *(const ushort8*)(A + (size_t)s * CDIM + c0);
    ushort8 ub = *(const ushort8*)(B + (size_t)d * CDIM + c0);
    f32x4 at0 = *(const f32x4*)(att + c0);
    f32x4 at1 = *(const f32x4*)(att + c0 + 4);

    float e = 0.0f;
#pragma unroll
    for (int i = 0; i < 4; ++i) {
        float v = bf2f(ua[i]) + bf2f(ub[i]);
        v = v > 0.0f ? v : NEG_SLOPE * v;
        e += v * at0[i];
        float w = bf2f(ua[4 + i]) + bf2f(ub[4 + i]);
        w = w > 0.0f ? w : NEG_SLOPE * w;
        e += w * at1[i];
    }
#pragma unroll
    for (int off = 8; off >= 1; off >>= 1) e += __shfl_xor(e, off, 16);

    if (sub == 0) {
        // |e| analytically bounded (~<10); no max-shift needed. Clamp = overflow armor.
        float ex = __expf(fminf(e, 60.0f));
        ee[eid] = ex;
        atomicAdd(&denom[d], ex);
    }
}

// ---- edge pass 2: R[dst,:] += (ee/denom[dst]) * xl[src,:]   (A bf16, R fp32)
__global__ __launch_bounds__(256)
void edge_agg(const int* __restrict__ src, const int* __restrict__ dst,
              const unsigned short* __restrict__ A, const float* __restrict__ ee,
              const float* __restrict__ denom, float* __restrict__ R, int n_edges) {
    int t = blockIdx.x * 256 + threadIdx.x;
    int eid = t >> 4;
    int sub = t & 15;
    if (eid >= n_edges) return;
    int s = clampi(src[eid], N_NODES);
    int d = clampi(dst[eid], N_NODES);
    float alpha = ee[eid] / fmaxf(denom[d], 1e-16f);
    int c0 = sub * 8;

    ushort8 ua = *(const ushort8*)(A + (size_t)s * CDIM + c0);
    float* rp = R + (size_t)d * CDIM + c0;
#pragma unroll
    for (int i = 0; i < 8; ++i) atomicAdd(rp + i, alpha * bf2f(ua[i]));
}

// ---- in-place ReLU on fp32 buffer (8 elems/thread) ----
__global__ __launch_bounds__(256)
void relu_inplace(float* __restrict__ R, int n_total) {
    int i = blockIdx.x * 256 + threadIdx.x;
    size_t base = (size_t)i * 8;
    if (base >= (size_t)n_total) return;
    f32x4 v0 = *(const f32x4*)(R + base);
    f32x4 v1 = *(const f32x4*)(R + base + 4);
#pragma unroll
    for (int k = 0; k < 4; ++k) { v0[k] = fmaxf(v0[k], 0.0f); v1[k] = fmaxf(v1[k], 0.0f); }
    *(f32x4*)(R + base) = v0;
    *(f32x4*)(R + base + 4) = v1;
}

static void run_layer(const float* xin,
                      const unsigned short* WT, const float* att, const float* bias,
                      unsigned short* A, unsigned short* B, float* R,
                      float* denom, float* ee,
                      const int* srcp, const int* dstp, hipStream_t stream) {
    dim3 gb((N_NODES + 63) / 64);
    proj3<<<gb, 256, 0, stream>>>(xin, WT, bias, A, B, R, N_NODES);
    hipMemsetAsync(denom, 0, N_NODES * sizeof(float), stream);
    int eb = (E_EDGES * 16 + 255) / 256;
    edge_logits<<<eb, 256, 0, stream>>>(srcp, dstp, A, B, att, ee, denom, E_EDGES);
    edge_agg<<<eb, 256, 0, stream>>>(srcp, dstp, A, ee, denom, R, E_EDGES);
    int rb = ((N_NODES * CDIM / 8) + 255) / 256;
    relu_inplace<<<rb, 256, 0, stream>>>(R, N_NODES * CDIM);
}

extern "C" void kernel_launch(void* const* d_in, const int* in_sizes, int n_in,
                              void* d_out, int out_size, void* d_ws, size_t ws_size,
                              hipStream_t stream) {
    const float* x     = (const float*)d_in[0];
    const int*   ei    = (const int*)d_in[1];
    const float* Wl1   = (const float*)d_in[2];
    const float* Wr1   = (const float*)d_in[3];
    const float* att1  = (const float*)d_in[4];
    const float* Wres1 = (const float*)d_in[5];
    const float* b1    = (const float*)d_in[6];
    const float* Wl2   = (const float*)d_in[7];
    const float* Wr2   = (const float*)d_in[8];
    const float* att2  = (const float*)d_in[9];
    const float* Wres2 = (const float*)d_in[10];
    const float* b2    = (const float*)d_in[11];

    const int* srcp = ei;
    const int* dstp = ei + E_EDGES;

    // ---- workspace carve (~54 MB) ----
    size_t off = 0;
    char* base = (char*)d_ws;
    auto carve = [&](size_t bytes) -> void* {
        void* q = base + off;
        off += (bytes + 255) & ~(size_t)255;
        return q;
    };
    // 6 weight mats x (hi,lo) x 16384 bf16 = 384 KB, order: Wl1,Wr1,Wres1,Wl2,Wr2,Wres2
    unsigned short* WT = (unsigned short*)carve((size_t)12 * 16384 * 2);
    unsigned short* A  = (unsigned short*)carve((size_t)N_NODES * CDIM * 2); // 25.6 MB
    unsigned short* B  = (unsigned short*)carve((size_t)N_NODES * CDIM * 2); // 25.6 MB
    float* denom = (float*)carve((size_t)N_NODES * 4);                       // 0.4 MB
    float* ee    = (float*)carve((size_t)E_EDGES * 4);                       // 2.0 MB
    (void)ws_size; (void)n_in; (void)in_sizes; (void)out_size;

    const float* Ws[6] = {Wl1, Wr1, Wres1, Wl2, Wr2, Wres2};
    for (int i = 0; i < 6; ++i)
        split_w<<<64, 256, 0, stream>>>(Ws[i], WT + (size_t)(2 * i) * 16384,
                                        WT + (size_t)(2 * i + 1) * 16384);

    float* R = (float*)d_out;   // fp32 accumulator lives in d_out for both layers;
                                // layer-2 proj3 reads X1==d_out and rewrites it in-place
                                // (block-exclusive rows; stores after reads).

    // layer 1: x -> relu(...) in d_out (fp32)
    run_layer(x, WT, att1, b1, A, B, R, denom, ee, srcp, dstp, stream);
    // layer 2: d_out -> relu(...) in d_out (fp32)
    run_layer((const float*)d_out, WT + (size_t)6 * 16384, att2, b2,
              A, B, R, denom, ee, srcp, dstp, stream);
}

// Round 4
// 733.383 us; speedup vs baseline: 5.5992x; 5.5992x over previous
//
#include <hip/hip_runtime.h>
#include <math.h>

#define N_NODES 100000
#define CDIM 128
#define E_EDGES 500000
#define NEG_SLOPE 0.2f
#define SCAN_CHUNK 1024   // 256 threads x 4 items
#define SCAN_NB ((N_NODES + SCAN_CHUNK - 1) / SCAN_CHUNK)

typedef __attribute__((ext_vector_type(8))) short short8;           // 8 bf16 (MFMA frag)
typedef __attribute__((ext_vector_type(4))) float f32x4;

static __device__ __forceinline__ float bf2f(unsigned short u) {
    unsigned int t = ((unsigned int)u) << 16;
    return __builtin_bit_cast(float, t);
}
static __device__ __forceinline__ unsigned short f2bf(float f) {
    unsigned int u = __builtin_bit_cast(unsigned int, f);
    unsigned int r = (u + 0x7FFFu + ((u >> 16) & 1u)) >> 16;   // RNE
    return (unsigned short)r;
}
static __device__ __forceinline__ int clampi(int v, int hi) {
    return v < 0 ? 0 : (v >= hi ? hi - 1 : v);
}

// ---- split one fp32 128x128 W into transposed bf16 hi/lo ----
__global__ void split_w(const float* __restrict__ W,
                        unsigned short* __restrict__ WTh,
                        unsigned short* __restrict__ WTl) {
    int idx = blockIdx.x * 256 + threadIdx.x;   // 0..16383
    int j = idx >> 7, k = idx & 127;
    float v = W[k * 128 + j];
    unsigned short h = f2bf(v);
    WTh[idx] = h;
    WTl[idx] = f2bf(v - bf2f(h));
}

// ---- fused 3-way projection: A=bf16(X@Wl), B=bf16(X@Wr), R=fp32(X@Wres+bias)
// Split-bf16: X@W = Xh@Wh + Xh@Wl + Xl@Wh (~fp32 accurate).
// In-place safe (R may alias X): each wave reads only its own 16 rows, stores after.
__global__ __launch_bounds__(256)
void proj3(const float* __restrict__ X,
           const unsigned short* __restrict__ WT,
           const float* __restrict__ bias,
           unsigned short* __restrict__ A,
           unsigned short* __restrict__ B,
           float* __restrict__ R, int n_rows) {
    const int lane = threadIdx.x & 63;
    const int wave = threadIdx.x >> 6;
    const int m    = lane & 15;
    const int quad = lane >> 4;
    const int row0 = blockIdx.x * 64 + wave * 16;

    int arow = row0 + m;
    if (arow >= n_rows) arow = n_rows - 1;

    const unsigned short* Wh[3] = {WT, WT + 2 * 16384, WT + 4 * 16384};
    const unsigned short* Wl[3] = {WT + 16384, WT + 3 * 16384, WT + 5 * 16384};

    f32x4 acc[3][8];
#pragma unroll
    for (int mi = 0; mi < 3; ++mi)
#pragma unroll
        for (int t = 0; t < 8; ++t) acc[mi][t] = (f32x4)0.0f;

#pragma unroll
    for (int kk = 0; kk < 4; ++kk) {
        const int kb = kk * 32 + quad * 8;
        const float* xp = X + (size_t)arow * CDIM + kb;
        f32x4 x0 = *(const f32x4*)xp;
        f32x4 x1 = *(const f32x4*)(xp + 4);
        short8 ah, al;
#pragma unroll
        for (int j = 0; j < 4; ++j) {
            unsigned short h0 = f2bf(x0[j]);
            ah[j] = (short)h0;
            al[j] = (short)f2bf(x0[j] - bf2f(h0));
            unsigned short h1 = f2bf(x1[j]);
            ah[4 + j] = (short)h1;
            al[4 + j] = (short)f2bf(x1[j] - bf2f(h1));
        }
#pragma unroll
        for (int t = 0; t < 8; ++t) {
            const size_t wo = (size_t)(t * 16 + m) * CDIM + kb;
#pragma unroll
            for (int mi = 0; mi < 3; ++mi) {
                short8 bh = *(const short8*)(Wh[mi] + wo);
                short8 bl = *(const short8*)(Wl[mi] + wo);
                acc[mi][t] = __builtin_amdgcn_mfma_f32_16x16x32_bf16(ah, bl, acc[mi][t], 0, 0, 0);
                acc[mi][t] = __builtin_amdgcn_mfma_f32_16x16x32_bf16(al, bh, acc[mi][t], 0, 0, 0);
                acc[mi][t] = __builtin_amdgcn_mfma_f32_16x16x32_bf16(ah, bh, acc[mi][t], 0, 0, 0);
            }
        }
    }

#pragma unroll
    for (int t = 0; t < 8; ++t) {
        const int col = t * 16 + m;
        const float bv = bias[col];
#pragma unroll
        for (int r = 0; r < 4; ++r) {
            const int row = row0 + quad * 4 + r;
            if (row < n_rows) {
                const size_t o = (size_t)row * CDIM + col;
                A[o] = f2bf(acc[0][t][r]);
                B[o] = f2bf(acc[1][t][r]);
                R[o] = acc[2][t][r] + bv;
            }
        }
    }
}

// ======================= CSR build (once per launch) =======================
__global__ __launch_bounds__(256)
void hist_dst(const int* __restrict__ dst, int* __restrict__ cnt, int n) {
    int e = blockIdx.x * 256 + threadIdx.x;
    if (e < n) atomicAdd(&cnt[clampi(dst[e], N_NODES)], 1);
}

// per-block inclusive scan of 1024 items; emits per-element inclusive + block total
__global__ __launch_bounds__(256)
void scan_local(const int* __restrict__ cnt, int* __restrict__ incl,
                int* __restrict__ blockSums, int n) {
    __shared__ int lds[256];
    int t = threadIdx.x;
    int base = blockIdx.x * SCAN_CHUNK + t * 4;
    int v[4], s = 0;
#pragma unroll
    for (int j = 0; j < 4; ++j) { v[j] = (base + j < n) ? cnt[base + j] : 0; s += v[j]; }
    lds[t] = s;
    __syncthreads();
    for (int off = 1; off < 256; off <<= 1) {
        int x = (t >= off) ? lds[t - off] : 0;
        __syncthreads();
        lds[t] += x;
        __syncthreads();
    }
    int run = lds[t] - s;   // exclusive prefix of this thread's chunk
#pragma unroll
    for (int j = 0; j < 4; ++j) {
        run += v[j];
        if (base + j < n) incl[base + j] = run;
    }
    if (t == 255) blockSums[blockIdx.x] = lds[255];
}

__global__ void scan_sums(int* __restrict__ blockSums, int nb) {
    if (threadIdx.x == 0 && blockIdx.x == 0) {
        int a = 0;
        for (int i = 0; i < nb; ++i) { int t = blockSums[i]; blockSums[i] = a; a += t; }
    }
}

__global__ __launch_bounds__(256)
void add_offsets(const int* __restrict__ incl, const int* __restrict__ blockSums,
                 const int* __restrict__ cnt, int* __restrict__ rowptr,
                 int* __restrict__ cursor, int n) {
    int i = blockIdx.x * 256 + threadIdx.x;
    if (i < n) {
        int v = incl[i] + blockSums[i / SCAN_CHUNK];
        rowptr[i + 1] = v;
        cursor[i] = v - cnt[i];
    }
    if (i == 0) rowptr[0] = 0;
}

__global__ __launch_bounds__(256)
void scatter_edges(const int* __restrict__ src, const int* __restrict__ dst,
                   int* __restrict__ cursor, int* __restrict__ esrc, int n) {
    int e = blockIdx.x * 256 + threadIdx.x;
    if (e < n) {
        int d = clampi(dst[e], N_NODES);
        int p = atomicAdd(&cursor[d], 1);
        esrc[p] = clampi(src[e], N_NODES);
    }
}

// ======================= fused edge phase =======================
// One wave per dst node; 2 channels per lane. Single pass:
//   den = Σ_j exp(e_j);  acc = Σ_j exp(e_j)·xl[s_j]   (alpha = ee/den folded in at end)
// Epilogue: R[d] = relu(R[d] + acc/den)   — atomic-free, replaces 3 kernels.
__global__ __launch_bounds__(256)
void fused_edge(const int* __restrict__ rowptr, const int* __restrict__ esrc,
                const unsigned short* __restrict__ A,
                const unsigned short* __restrict__ B,
                const float* __restrict__ att,
                float* __restrict__ R, int n_nodes) {
    const int wave = threadIdx.x >> 6;
    const int lane = threadIdx.x & 63;
    const int d = blockIdx.x * 4 + wave;
    if (d >= n_nodes) return;
    const int c0 = lane * 2;

    unsigned int ub = *(const unsigned int*)(B + (size_t)d * CDIM + c0);
    const float b0 = bf2f((unsigned short)(ub & 0xffff));
    const float b1 = bf2f((unsigned short)(ub >> 16));
    const float at0 = att[c0];
    const float at1 = att[c0 + 1];

    float acc0 = 0.0f, acc1 = 0.0f, den = 0.0f;
    const int p0 = rowptr[d], p1 = rowptr[d + 1];
    for (int p = p0; p < p1; ++p) {
        int s = esrc[p];
        unsigned int ua = *(const unsigned int*)(A + (size_t)s * CDIM + c0);
        float a0 = bf2f((unsigned short)(ua & 0xffff));
        float a1 = bf2f((unsigned short)(ua >> 16));
        float v0 = a0 + b0; v0 = v0 > 0.0f ? v0 : NEG_SLOPE * v0;
        float v1 = a1 + b1; v1 = v1 > 0.0f ? v1 : NEG_SLOPE * v1;
        float e = v0 * at0 + v1 * at1;
#pragma unroll
        for (int off = 32; off >= 1; off >>= 1) e += __shfl_xor(e, off, 64);
        float ee = __expf(fminf(e, 60.0f));   // |e| analytically << 60; clamp = armor
        den += ee;
        acc0 += ee * a0;
        acc1 += ee * a1;
    }
    float inv = 1.0f / fmaxf(den, 1e-16f);
    float* rp = R + (size_t)d * CDIM + c0;
    float2 r = *(const float2*)rp;
    r.x = fmaxf(r.x + acc0 * inv, 0.0f);
    r.y = fmaxf(r.y + acc1 * inv, 0.0f);
    *(float2*)rp = r;
}

static void run_layer(const float* xin,
                      const unsigned short* WT, const float* att, const float* bias,
                      unsigned short* A, unsigned short* B, float* R,
                      const int* rowptr, const int* esrc, hipStream_t stream) {
    dim3 gb((N_NODES + 63) / 64);
    proj3<<<gb, 256, 0, stream>>>(xin, WT, bias, A, B, R, N_NODES);
    fused_edge<<<(N_NODES + 3) / 4, 256, 0, stream>>>(rowptr, esrc, A, B, att, R, N_NODES);
}

extern "C" void kernel_launch(void* const* d_in, const int* in_sizes, int n_in,
                              void* d_out, int out_size, void* d_ws, size_t ws_size,
                              hipStream_t stream) {
    const float* x     = (const float*)d_in[0];
    const int*   ei    = (const int*)d_in[1];
    const float* Wl1   = (const float*)d_in[2];
    const float* Wr1   = (const float*)d_in[3];
    const float* att1  = (const float*)d_in[4];
    const float* Wres1 = (const float*)d_in[5];
    const float* b1    = (const float*)d_in[6];
    const float* Wl2   = (const float*)d_in[7];
    const float* Wr2   = (const float*)d_in[8];
    const float* att2  = (const float*)d_in[9];
    const float* Wres2 = (const float*)d_in[10];
    const float* b2    = (const float*)d_in[11];

    const int* srcp = ei;
    const int* dstp = ei + E_EDGES;

    // ---- workspace carve (~56 MB) ----
    size_t off = 0;
    char* base = (char*)d_ws;
    auto carve = [&](size_t bytes) -> void* {
        void* q = base + off;
        off += (bytes + 255) & ~(size_t)255;
        return q;
    };
    unsigned short* WT = (unsigned short*)carve((size_t)12 * 16384 * 2);       // 384 KB
    unsigned short* A  = (unsigned short*)carve((size_t)N_NODES * CDIM * 2);   // 25.6 MB
    unsigned short* B  = (unsigned short*)carve((size_t)N_NODES * CDIM * 2);   // 25.6 MB
    int* cnt      = (int*)carve((size_t)N_NODES * 4);                          // 0.4 MB
    int* rowptr   = (int*)carve((size_t)(N_NODES + 1) * 4);                    // 0.4 MB
    int* cursor   = (int*)carve((size_t)N_NODES * 4);                          // 0.4 MB
    int* esrc     = (int*)carve((size_t)E_EDGES * 4);                          // 2.0 MB
    int* incl     = (int*)carve((size_t)N_NODES * 4);                          // 0.4 MB
    int* blockSums= (int*)carve((size_t)SCAN_NB * 4);
    (void)ws_size; (void)n_in; (void)in_sizes; (void)out_size;

    // ---- weight prep ----
    const float* Ws[6] = {Wl1, Wr1, Wres1, Wl2, Wr2, Wres2};
    for (int i = 0; i < 6; ++i)
        split_w<<<64, 256, 0, stream>>>(Ws[i], WT + (size_t)(2 * i) * 16384,
                                        WT + (size_t)(2 * i + 1) * 16384);

    // ---- CSR build (dst-grouped), reused by both layers ----
    hipMemsetAsync(cnt, 0, (size_t)N_NODES * 4, stream);
    hist_dst<<<(E_EDGES + 255) / 256, 256, 0, stream>>>(dstp, cnt, E_EDGES);
    scan_local<<<SCAN_NB, 256, 0, stream>>>(cnt, incl, blockSums, N_NODES);
    scan_sums<<<1, 64, 0, stream>>>(blockSums, SCAN_NB);
    add_offsets<<<(N_NODES + 255) / 256, 256, 0, stream>>>(incl, blockSums, cnt,
                                                           rowptr, cursor, N_NODES);
    scatter_edges<<<(E_EDGES + 255) / 256, 256, 0, stream>>>(srcp, dstp, cursor,
                                                             esrc, E_EDGES);

    float* R = (float*)d_out;   // fp32 accumulator in d_out for both layers;
                                // layer-2 proj3 reads X1==d_out in place (wave-exclusive rows).
    run_layer(x, WT, att1, b1, A, B, R, rowptr, esrc, stream);
    run_layer((const float*)d_out, WT + (size_t)6 * 16384, att2, b2,
              A, B, R, rowptr, esrc, stream);
}

// Round 5
// 517.674 us; speedup vs baseline: 7.9323x; 1.4167x over previous
//
#include <hip/hip_runtime.h>
#include <math.h>

#define N_NODES 100000
#define CDIM 128
#define E_EDGES 500000
#define NEG_SLOPE 0.2f
#define SCAN_CHUNK 1024   // 256 threads x 4 items
#define SCAN_NB ((N_NODES + SCAN_CHUNK - 1) / SCAN_CHUNK)
#define NSTRIPS ((N_NODES + 63) / 64)

typedef __attribute__((ext_vector_type(8))) short short8;           // 8 bf16 (MFMA frag)
typedef __attribute__((ext_vector_type(8))) unsigned short ushort8;
typedef __attribute__((ext_vector_type(4))) float f32x4;

static __device__ __forceinline__ float bf2f(unsigned short u) {
    unsigned int t = ((unsigned int)u) << 16;
    return __builtin_bit_cast(float, t);
}
static __device__ __forceinline__ unsigned short f2bf(float f) {
    unsigned int u = __builtin_bit_cast(unsigned int, f);
    unsigned int r = (u + 0x7FFFu + ((u >> 16) & 1u)) >> 16;   // RNE
    return (unsigned short)r;
}
static __device__ __forceinline__ int clampi(int v, int hi) {
    return v < 0 ? 0 : (v >= hi ? hi - 1 : v);
}

// ---- pack one fp32 128x128 W into MFMA-fragment-major bf16 ----
// chunk(kk,t) at ((kk*8+t)*64)*8 shorts; lane l (m=l&15,q=l>>4) owns 8 shorts:
// W[kk*32+q*8+u][t*16+m], u=0..7.  16384 shorts = 32 KB per matrix.
__global__ __launch_bounds__(256)
void pack_w(const float* __restrict__ W, unsigned short* __restrict__ Wf) {
    int rem = blockIdx.x * 256 + threadIdx.x;   // 0..2047
    if (rem >= 2048) return;
    int l  = rem & 63;
    int t  = (rem >> 6) & 7;
    int kk = rem >> 9;
    int m = l & 15, q = l >> 4;
    int j = t * 16 + m;
    int k0 = kk * 32 + q * 8;
    ushort8 o;
#pragma unroll
    for (int u = 0; u < 8; ++u) o[u] = f2bf(W[(k0 + u) * 128 + j]);
    *(ushort8*)(Wf + (size_t)rem * 8) = o;
}

// ---- fused 3-way projection: A=bf16(X@Wl), B=bf16(X@Wr), R=fp32(X@Wres+bias)
// X split hi/lo (fp32-accurate X); W in bf16 (frag-major). Wl/Wr frags staged in
// 64 KB LDS once per block; Wres frags streamed from L2 (coalesced frag layout).
// Grid-stride over 64-row strips; in-place safe (each wave reads only its 16 rows,
// stores after its reads; strips disjoint).
__global__ __launch_bounds__(256)
void proj3(const float* __restrict__ X,
           const unsigned short* __restrict__ WfL,
           const unsigned short* __restrict__ WfR,
           const unsigned short* __restrict__ WfRes,
           const float* __restrict__ bias,
           unsigned short* __restrict__ A,
           unsigned short* __restrict__ B,
           float* __restrict__ R, int n_rows) {
    __shared__ unsigned short lds[32768];   // 64 KB: [0..16383]=Wl frags, [16384..]=Wr
    const int tid = threadIdx.x;
    for (int i = tid; i < 2048; i += 256) {
        *(ushort8*)(lds + (size_t)i * 8)         = *(const ushort8*)(WfL + (size_t)i * 8);
        *(ushort8*)(lds + 16384 + (size_t)i * 8) = *(const ushort8*)(WfR + (size_t)i * 8);
    }
    __syncthreads();

    const int wave = tid >> 6;
    const int lane = tid & 63;
    const int m    = lane & 15;
    const int q    = lane >> 4;

    for (int strip = blockIdx.x; strip < NSTRIPS; strip += gridDim.x) {
        const int row0 = strip * 64 + wave * 16;
        int arow = row0 + m;
        if (arow >= n_rows) arow = n_rows - 1;

        f32x4 acc[3][8];
#pragma unroll
        for (int mi = 0; mi < 3; ++mi)
#pragma unroll
            for (int t = 0; t < 8; ++t) acc[mi][t] = (f32x4)0.0f;

#pragma unroll
        for (int kk = 0; kk < 4; ++kk) {
            const float* xp = X + (size_t)arow * CDIM + kk * 32 + q * 8;
            f32x4 x0 = *(const f32x4*)xp;
            f32x4 x1 = *(const f32x4*)(xp + 4);
            short8 ah, al;
#pragma unroll
            for (int j = 0; j < 4; ++j) {
                unsigned short h0 = f2bf(x0[j]);
                ah[j] = (short)h0;
                al[j] = (short)f2bf(x0[j] - bf2f(h0));
                unsigned short h1 = f2bf(x1[j]);
                ah[4 + j] = (short)h1;
                al[4 + j] = (short)f2bf(x1[j] - bf2f(h1));
            }
#pragma unroll
            for (int t = 0; t < 8; ++t) {
                const size_t ci = ((size_t)(kk * 8 + t) * 64 + lane) * 8;
                short8 bl_ = *(const short8*)(lds + ci);
                short8 br_ = *(const short8*)(lds + 16384 + ci);
                short8 bs_ = *(const short8*)(WfRes + ci);
                acc[0][t] = __builtin_amdgcn_mfma_f32_16x16x32_bf16(ah, bl_, acc[0][t], 0, 0, 0);
                acc[0][t] = __builtin_amdgcn_mfma_f32_16x16x32_bf16(al, bl_, acc[0][t], 0, 0, 0);
                acc[1][t] = __builtin_amdgcn_mfma_f32_16x16x32_bf16(ah, br_, acc[1][t], 0, 0, 0);
                acc[1][t] = __builtin_amdgcn_mfma_f32_16x16x32_bf16(al, br_, acc[1][t], 0, 0, 0);
                acc[2][t] = __builtin_amdgcn_mfma_f32_16x16x32_bf16(ah, bs_, acc[2][t], 0, 0, 0);
                acc[2][t] = __builtin_amdgcn_mfma_f32_16x16x32_bf16(al, bs_, acc[2][t], 0, 0, 0);
            }
        }

#pragma unroll
        for (int t = 0; t < 8; ++t) {
            const int col = t * 16 + m;
            const float bv = bias[col];
#pragma unroll
            for (int r = 0; r < 4; ++r) {
                const int row = row0 + q * 4 + r;
                if (row < n_rows) {
                    const size_t o = (size_t)row * CDIM + col;
                    A[o] = f2bf(acc[0][t][r]);
                    B[o] = f2bf(acc[1][t][r]);
                    R[o] = acc[2][t][r] + bv;
                }
            }
        }
    }
}

// ======================= CSR build (once per launch) =======================
__global__ __launch_bounds__(256)
void hist_dst(const int* __restrict__ dst, int* __restrict__ cnt, int n) {
    int e = blockIdx.x * 256 + threadIdx.x;
    if (e < n) atomicAdd(&cnt[clampi(dst[e], N_NODES)], 1);
}

__global__ __launch_bounds__(256)
void scan_local(const int* __restrict__ cnt, int* __restrict__ incl,
                int* __restrict__ blockSums, int n) {
    __shared__ int lds[256];
    int t = threadIdx.x;
    int base = blockIdx.x * SCAN_CHUNK + t * 4;
    int v[4], s = 0;
#pragma unroll
    for (int j = 0; j < 4; ++j) { v[j] = (base + j < n) ? cnt[base + j] : 0; s += v[j]; }
    lds[t] = s;
    __syncthreads();
    for (int off = 1; off < 256; off <<= 1) {
        int x = (t >= off) ? lds[t - off] : 0;
        __syncthreads();
        lds[t] += x;
        __syncthreads();
    }
    int run = lds[t] - s;
#pragma unroll
    for (int j = 0; j < 4; ++j) {
        run += v[j];
        if (base + j < n) incl[base + j] = run;
    }
    if (t == 255) blockSums[blockIdx.x] = lds[255];
}

__global__ void scan_sums(int* __restrict__ blockSums, int nb) {
    if (threadIdx.x == 0 && blockIdx.x == 0) {
        int a = 0;
        for (int i = 0; i < nb; ++i) { int t = blockSums[i]; blockSums[i] = a; a += t; }
    }
}

__global__ __launch_bounds__(256)
void add_offsets(const int* __restrict__ incl, const int* __restrict__ blockSums,
                 const int* __restrict__ cnt, int* __restrict__ rowptr,
                 int* __restrict__ cursor, int n) {
    int i = blockIdx.x * 256 + threadIdx.x;
    if (i < n) {
        int v = incl[i] + blockSums[i / SCAN_CHUNK];
        rowptr[i + 1] = v;
        cursor[i] = v - cnt[i];
    }
    if (i == 0) rowptr[0] = 0;
}

__global__ __launch_bounds__(256)
void scatter_edges(const int* __restrict__ src, const int* __restrict__ dst,
                   int* __restrict__ cursor, int* __restrict__ esrc, int n) {
    int e = blockIdx.x * 256 + threadIdx.x;
    if (e < n) {
        int d = clampi(dst[e], N_NODES);
        int p = atomicAdd(&cursor[d], 1);
        esrc[p] = clampi(src[e], N_NODES);
    }
}

// ======================= fused edge phase =======================
// One wave per dst node; 2 channels/lane. den = Σ exp(e); acc = Σ exp(e)·xl[src].
// Epilogue: R[d] = relu(R[d] + acc/den). Atomic-free.
__global__ __launch_bounds__(256)
void fused_edge(const int* __restrict__ rowptr, const int* __restrict__ esrc,
                const unsigned short* __restrict__ A,
                const unsigned short* __restrict__ B,
                const float* __restrict__ att,
                float* __restrict__ R, int n_nodes) {
    const int wave = threadIdx.x >> 6;
    const int lane = threadIdx.x & 63;
    const int d = blockIdx.x * 4 + wave;
    if (d >= n_nodes) return;
    const int c0 = lane * 2;

    unsigned int ub = *(const unsigned int*)(B + (size_t)d * CDIM + c0);
    const float b0 = bf2f((unsigned short)(ub & 0xffff));
    const float b1 = bf2f((unsigned short)(ub >> 16));
    const float at0 = att[c0];
    const float at1 = att[c0 + 1];

    float acc0 = 0.0f, acc1 = 0.0f, den = 0.0f;
    const int p0 = rowptr[d], p1 = rowptr[d + 1];
    for (int p = p0; p < p1; ++p) {
        int s = esrc[p];
        unsigned int ua = *(const unsigned int*)(A + (size_t)s * CDIM + c0);
        float a0 = bf2f((unsigned short)(ua & 0xffff));
        float a1 = bf2f((unsigned short)(ua >> 16));
        float v0 = a0 + b0; v0 = v0 > 0.0f ? v0 : NEG_SLOPE * v0;
        float v1 = a1 + b1; v1 = v1 > 0.0f ? v1 : NEG_SLOPE * v1;
        float e = v0 * at0 + v1 * at1;
#pragma unroll
        for (int off = 32; off >= 1; off >>= 1) e += __shfl_xor(e, off, 64);
        float ee = __expf(fminf(e, 60.0f));   // |e| analytically << 60; clamp = armor
        den += ee;
        acc0 += ee * a0;
        acc1 += ee * a1;
    }
    float inv = 1.0f / fmaxf(den, 1e-16f);
    float* rp = R + (size_t)d * CDIM + c0;
    float2 r = *(const float2*)rp;
    r.x = fmaxf(r.x + acc0 * inv, 0.0f);
    r.y = fmaxf(r.y + acc1 * inv, 0.0f);
    *(float2*)rp = r;
}

static void run_layer(const float* xin, const unsigned short* Wf,
                      const float* att, const float* bias,
                      unsigned short* A, unsigned short* B, float* R,
                      const int* rowptr, const int* esrc, hipStream_t stream) {
    proj3<<<512, 256, 0, stream>>>(xin, Wf, Wf + 16384, Wf + 32768,
                                   bias, A, B, R, N_NODES);
    fused_edge<<<(N_NODES + 3) / 4, 256, 0, stream>>>(rowptr, esrc, A, B, att, R, N_NODES);
}

extern "C" void kernel_launch(void* const* d_in, const int* in_sizes, int n_in,
                              void* d_out, int out_size, void* d_ws, size_t ws_size,
                              hipStream_t stream) {
    const float* x     = (const float*)d_in[0];
    const int*   ei    = (const int*)d_in[1];
    const float* Wl1   = (const float*)d_in[2];
    const float* Wr1   = (const float*)d_in[3];
    const float* att1  = (const float*)d_in[4];
    const float* Wres1 = (const float*)d_in[5];
    const float* b1    = (const float*)d_in[6];
    const float* Wl2   = (const float*)d_in[7];
    const float* Wr2   = (const float*)d_in[8];
    const float* att2  = (const float*)d_in[9];
    const float* Wres2 = (const float*)d_in[10];
    const float* b2    = (const float*)d_in[11];

    const int* srcp = ei;
    const int* dstp = ei + E_EDGES;

    // ---- workspace carve (~56 MB) ----
    size_t off = 0;
    char* base = (char*)d_ws;
    auto carve = [&](size_t bytes) -> void* {
        void* q = base + off;
        off += (bytes + 255) & ~(size_t)255;
        return q;
    };
    // frag-major weights: 6 mats x 16384 shorts (order Wl1,Wr1,Wres1,Wl2,Wr2,Wres2)
    unsigned short* Wf = (unsigned short*)carve((size_t)6 * 16384 * 2);        // 192 KB
    unsigned short* A  = (unsigned short*)carve((size_t)N_NODES * CDIM * 2);   // 25.6 MB
    unsigned short* B  = (unsigned short*)carve((size_t)N_NODES * CDIM * 2);   // 25.6 MB
    int* cnt      = (int*)carve((size_t)N_NODES * 4);
    int* rowptr   = (int*)carve((size_t)(N_NODES + 1) * 4);
    int* cursor   = (int*)carve((size_t)N_NODES * 4);
    int* esrc     = (int*)carve((size_t)E_EDGES * 4);
    int* incl     = (int*)carve((size_t)N_NODES * 4);
    int* blockSums= (int*)carve((size_t)SCAN_NB * 4);
    (void)ws_size; (void)n_in; (void)in_sizes; (void)out_size;

    // ---- weight prep: fragment-major pack ----
    const float* Ws[6] = {Wl1, Wr1, Wres1, Wl2, Wr2, Wres2};
    for (int i = 0; i < 6; ++i)
        pack_w<<<8, 256, 0, stream>>>(Ws[i], Wf + (size_t)i * 16384);

    // ---- CSR build (dst-grouped), reused by both layers ----
    hipMemsetAsync(cnt, 0, (size_t)N_NODES * 4, stream);
    hist_dst<<<(E_EDGES + 255) / 256, 256, 0, stream>>>(dstp, cnt, E_EDGES);
    scan_local<<<SCAN_NB, 256, 0, stream>>>(cnt, incl, blockSums, N_NODES);
    scan_sums<<<1, 64, 0, stream>>>(blockSums, SCAN_NB);
    add_offsets<<<(N_NODES + 255) / 256, 256, 0, stream>>>(incl, blockSums, cnt,
                                                           rowptr, cursor, N_NODES);
    scatter_edges<<<(E_EDGES + 255) / 256, 256, 0, stream>>>(srcp, dstp, cursor,
                                                             esrc, E_EDGES);

    float* R = (float*)d_out;   // fp32 accumulator in d_out for both layers;
                                // layer-2 proj3 reads X1==d_out in place (wave-exclusive rows).
    run_layer(x, Wf, att1, b1, A, B, R, rowptr, esrc, stream);
    run_layer((const float*)d_out, Wf + (size_t)3 * 16384, att2, b2,
              A, B, R, rowptr, esrc, stream);
}

// Round 7
// 396.022 us; speedup vs baseline: 10.3690x; 1.3072x over previous
//
#include <hip/hip_runtime.h>
#include <math.h>

#define N_NODES 100000
#define CDIM 128
#define E_EDGES 500000
#define NEG_SLOPE 0.2f
#define SCAN_CHUNK 1024   // 256 threads x 4 items
#define SCAN_NB ((N_NODES + SCAN_CHUNK - 1) / SCAN_CHUNK)   // 98
#define NSTRIPS ((N_NODES + 63) / 64)                       // 1563

typedef __attribute__((ext_vector_type(8))) short short8;             // 8 bf16 (MFMA frag)
typedef __attribute__((ext_vector_type(8))) unsigned short ushort8;
typedef __attribute__((ext_vector_type(4))) unsigned short u16x4;
typedef __attribute__((ext_vector_type(4))) float f32x4;

static __device__ __forceinline__ float bf2f(unsigned short u) {
    unsigned int t = ((unsigned int)u) << 16;
    return __builtin_bit_cast(float, t);
}
static __device__ __forceinline__ unsigned short f2bf(float f) {
    unsigned int u = __builtin_bit_cast(unsigned int, f);
    unsigned int r = (u + 0x7FFFu + ((u >> 16) & 1u)) >> 16;   // RNE
    return (unsigned short)r;
}
static __device__ __forceinline__ int clampi(int v, int hi) {
    return v < 0 ? 0 : (v >= hi ? hi - 1 : v);
}
static __device__ __forceinline__ float lrelu(float v) {
    return v > 0.0f ? v : NEG_SLOPE * v;
}

// ---- pack all 6 fp32 128x128 W into MFMA-fragment-major bf16 ----
// chunk(kk,t): lane l (m=l&15,q=l>>4) owns W[kk*32+q*8+u][t*16+m], u=0..7.
// 2048 chunks x 16B = 32 KB per matrix. 8 blocks per matrix.
__global__ __launch_bounds__(256)
void pack_w_all(const float* __restrict__ W0, const float* __restrict__ W1,
                const float* __restrict__ W2, const float* __restrict__ W3,
                const float* __restrict__ W4, const float* __restrict__ W5,
                unsigned short* __restrict__ Wf) {
    const float* Wp[6] = {W0, W1, W2, W3, W4, W5};
    int mi  = blockIdx.x >> 3;                       // 0..5 (block-uniform)
    int rem = ((blockIdx.x & 7) << 8) | threadIdx.x; // 0..2047
    const float* W = Wp[mi];
    int l = rem & 63, t = (rem >> 6) & 7, kk = rem >> 9;
    int m = l & 15, q = l >> 4;
    int j = t * 16 + m;
    int k0 = kk * 32 + q * 8;
    ushort8 o;
#pragma unroll
    for (int u = 0; u < 8; ++u) o[u] = f2bf(W[(k0 + u) * 128 + j]);
    *(ushort8*)(Wf + ((size_t)mi * 2048 + rem) * 8) = o;
}

// ---- single-matrix projection, one matrix per block (blockIdx.x = 0:Wl,1:Wr,2:Wres)
// a-operand = W frag, b-operand = X frag  ->  acc[t][r] = out[row0+lane%16][t*16+quad*4+r]
// (each lane owns 4 consecutive cols of ONE row -> wide stores).
// XSPLIT: X fp32, hi/lo split (fp32-accurate). !XSPLIT: X bf16, direct frag (half MFMAs).
// No LDS; W frags (32KB/mat) read via L1/L2. acc = 32 VGPR -> high occupancy.
template <bool XSPLIT>
__global__ __launch_bounds__(256)
void proj1(const void* __restrict__ Xv,
           const unsigned short* __restrict__ Wf,    // 3 mats, frag-major
           const float* __restrict__ bias,
           unsigned short* __restrict__ Aout,
           unsigned short* __restrict__ Bout,
           float* __restrict__ Rout, int n_rows) {
    const int mat  = blockIdx.x;           // 0,1,2
    const int wave = threadIdx.x >> 6;
    const int lane = threadIdx.x & 63;
    const int m = lane & 15, q = lane >> 4;
    const int row0 = blockIdx.y * 64 + wave * 16;
    const int xrow = row0 + m;                         // this lane's output row
    const int arow = xrow < n_rows ? xrow : n_rows - 1;
    const unsigned short* W = Wf + (size_t)mat * 16384;

    f32x4 acc[8];
#pragma unroll
    for (int t = 0; t < 8; ++t) acc[t] = (f32x4)0.0f;

#pragma unroll
    for (int kk = 0; kk < 4; ++kk) {
        short8 xh, xl_;
        if (XSPLIT) {
            const float* xp = (const float*)Xv + (size_t)arow * CDIM + kk * 32 + q * 8;
            f32x4 x0 = *(const f32x4*)xp;
            f32x4 x1 = *(const f32x4*)(xp + 4);
#pragma unroll
            for (int j = 0; j < 4; ++j) {
                unsigned short h0 = f2bf(x0[j]);
                xh[j] = (short)h0;
                xl_[j] = (short)f2bf(x0[j] - bf2f(h0));
                unsigned short h1 = f2bf(x1[j]);
                xh[4 + j] = (short)h1;
                xl_[4 + j] = (short)f2bf(x1[j] - bf2f(h1));
            }
        } else {
            xh = *(const short8*)((const unsigned short*)Xv +
                                  (size_t)arow * CDIM + kk * 32 + q * 8);
        }
#pragma unroll
        for (int t = 0; t < 8; ++t) {
            short8 w = *(const short8*)(W + ((size_t)(kk * 8 + t) * 64 + lane) * 8);
            acc[t] = __builtin_amdgcn_mfma_f32_16x16x32_bf16(w, xh, acc[t], 0, 0, 0);
            if (XSPLIT)
                acc[t] = __builtin_amdgcn_mfma_f32_16x16x32_bf16(w, xl_, acc[t], 0, 0, 0);
        }
    }

    if (xrow < n_rows) {
        if (mat < 2) {
            unsigned short* O = (mat == 0 ? Aout : Bout);
#pragma unroll
            for (int t = 0; t < 8; ++t) {
                u16x4 o4;
#pragma unroll
                for (int r = 0; r < 4; ++r) o4[r] = f2bf(acc[t][r]);
                *(u16x4*)(O + (size_t)xrow * CDIM + t * 16 + q * 4) = o4;
            }
        } else {
#pragma unroll
            for (int t = 0; t < 8; ++t) {
                f32x4 bv = *(const f32x4*)(bias + t * 16 + q * 4);
                f32x4 o = acc[t] + bv;
                *(f32x4*)(Rout + (size_t)xrow * CDIM + t * 16 + q * 4) = o;
            }
        }
    }
}

// ======================= CSR build (once per launch) =======================
__global__ __launch_bounds__(256)
void hist_dst(const int* __restrict__ dst, int* __restrict__ cnt, int n) {
    int e = blockIdx.x * 256 + threadIdx.x;
    if (e < n) atomicAdd(&cnt[clampi(dst[e], N_NODES)], 1);
}

__global__ __launch_bounds__(256)
void scan_local(const int* __restrict__ cnt, int* __restrict__ incl,
                int* __restrict__ blockSums, int n) {
    __shared__ int lds[256];
    int t = threadIdx.x;
    int base = blockIdx.x * SCAN_CHUNK + t * 4;
    int v[4], s = 0;
#pragma unroll
    for (int j = 0; j < 4; ++j) { v[j] = (base + j < n) ? cnt[base + j] : 0; s += v[j]; }
    lds[t] = s;
    __syncthreads();
    for (int off = 1; off < 256; off <<= 1) {
        int x = (t >= off) ? lds[t - off] : 0;
        __syncthreads();
        lds[t] += x;
        __syncthreads();
    }
    int run = lds[t] - s;
#pragma unroll
    for (int j = 0; j < 4; ++j) {
        run += v[j];
        if (base + j < n) incl[base + j] = run;
    }
    if (t == 255) blockSums[blockIdx.x] = lds[255];
}

// parallel exclusive scan of the (<=128) block totals
__global__ __launch_bounds__(128)
void scan_sums(int* __restrict__ blockSums, int nb) {
    __shared__ int lds[128];
    int t = threadIdx.x;
    int v = (t < nb) ? blockSums[t] : 0;
    lds[t] = v;
    __syncthreads();
    for (int off = 1; off < 128; off <<= 1) {
        int x = (t >= off) ? lds[t - off] : 0;
        __syncthreads();
        lds[t] += x;
        __syncthreads();
    }
    if (t < nb) blockSums[t] = lds[t] - v;   // exclusive
}

__global__ __launch_bounds__(256)
void add_offsets(const int* __restrict__ incl, const int* __restrict__ blockSums,
                 const int* __restrict__ cnt, int* __restrict__ rowptr,
                 int* __restrict__ cursor, int n) {
    int i = blockIdx.x * 256 + threadIdx.x;
    if (i < n) {
        int v = incl[i] + blockSums[i / SCAN_CHUNK];
        rowptr[i + 1] = v;
        cursor[i] = v - cnt[i];
    }
    if (i == 0) rowptr[0] = 0;
}

__global__ __launch_bounds__(256)
void scatter_edges(const int* __restrict__ src, const int* __restrict__ dst,
                   int* __restrict__ cursor, int* __restrict__ esrc, int n) {
    int e = blockIdx.x * 256 + threadIdx.x;
    if (e < n) {
        int d = clampi(dst[e], N_NODES);
        int p = atomicAdd(&cursor[d], 1);
        esrc[p] = clampi(src[e], N_NODES);
    }
}

// ======================= fused edge phase =======================
// One wave per dst node; 2 ch/lane. den = sum exp(e); acc = sum exp(e)*xl[src].
// 2-edge unroll: two independent shuffle chains interleaved (latency hiding).
// Epilogue: Out[d] = relu(Rin[d] + acc/den).  BF16OUT: Out bf16 else fp32.
template <bool BF16OUT>
__global__ __launch_bounds__(256)
void fused_edge(const int* __restrict__ rowptr, const int* __restrict__ esrc,
                const unsigned short* __restrict__ A,
                const unsigned short* __restrict__ B,
                const float* __restrict__ att,
                const float* __restrict__ Rin, void* __restrict__ Outv, int n_nodes) {
    const int wave = threadIdx.x >> 6;
    const int lane = threadIdx.x & 63;
    const int d = blockIdx.x * 4 + wave;
    if (d >= n_nodes) return;
    const int c0 = lane * 2;

    unsigned int ub = *(const unsigned int*)(B + (size_t)d * CDIM + c0);
    const float b0 = bf2f((unsigned short)(ub & 0xffff));
    const float b1 = bf2f((unsigned short)(ub >> 16));
    const float at0 = att[c0];
    const float at1 = att[c0 + 1];

    float acc0 = 0.0f, acc1 = 0.0f, den = 0.0f;
    const int p0 = rowptr[d], p1 = rowptr[d + 1];
    int p = p0;
    for (; p + 2 <= p1; p += 2) {
        int s0 = esrc[p], s1 = esrc[p + 1];
        unsigned int ua0 = *(const unsigned int*)(A + (size_t)s0 * CDIM + c0);
        unsigned int ua1 = *(const unsigned int*)(A + (size_t)s1 * CDIM + c0);
        float a00 = bf2f((unsigned short)(ua0 & 0xffff));
        float a01 = bf2f((unsigned short)(ua0 >> 16));
        float a10 = bf2f((unsigned short)(ua1 & 0xffff));
        float a11 = bf2f((unsigned short)(ua1 >> 16));
        float e0 = lrelu(a00 + b0) * at0 + lrelu(a01 + b1) * at1;
        float e1 = lrelu(a10 + b0) * at0 + lrelu(a11 + b1) * at1;
#pragma unroll
        for (int off = 32; off >= 1; off >>= 1) {
            e0 += __shfl_xor(e0, off, 64);
            e1 += __shfl_xor(e1, off, 64);
        }
        float ee0 = __expf(fminf(e0, 60.0f));   // |e| analytically << 60; clamp = armor
        float ee1 = __expf(fminf(e1, 60.0f));
        den  += ee0 + ee1;
        acc0 += ee0 * a00 + ee1 * a10;
        acc1 += ee0 * a01 + ee1 * a11;
    }
    if (p < p1) {
        int s0 = esrc[p];
        unsigned int ua0 = *(const unsigned int*)(A + (size_t)s0 * CDIM + c0);
        float a00 = bf2f((unsigned short)(ua0 & 0xffff));
        float a01 = bf2f((unsigned short)(ua0 >> 16));
        float e0 = lrelu(a00 + b0) * at0 + lrelu(a01 + b1) * at1;
#pragma unroll
        for (int off = 32; off >= 1; off >>= 1) e0 += __shfl_xor(e0, off, 64);
        float ee0 = __expf(fminf(e0, 60.0f));
        den  += ee0;
        acc0 += ee0 * a00;
        acc1 += ee0 * a01;
    }

    float inv = 1.0f / fmaxf(den, 1e-16f);
    const float* rp = Rin + (size_t)d * CDIM + c0;
    float2 r = *(const float2*)rp;
    float o0 = fmaxf(r.x + acc0 * inv, 0.0f);
    float o1 = fmaxf(r.y + acc1 * inv, 0.0f);
    if (BF16OUT) {
        unsigned int pk = (unsigned int)f2bf(o0) | ((unsigned int)f2bf(o1) << 16);
        *(unsigned int*)((unsigned short*)Outv + (size_t)d * CDIM + c0) = pk;
    } else {
        *(float2*)((float*)Outv + (size_t)d * CDIM + c0) = make_float2(o0, o1);
    }
}

extern "C" void kernel_launch(void* const* d_in, const int* in_sizes, int n_in,
                              void* d_out, int out_size, void* d_ws, size_t ws_size,
                              hipStream_t stream) {
    const float* x     = (const float*)d_in[0];
    const int*   ei    = (const int*)d_in[1];
    const float* Wl1   = (const float*)d_in[2];
    const float* Wr1   = (const float*)d_in[3];
    const float* att1  = (const float*)d_in[4];
    const float* Wres1 = (const float*)d_in[5];
    const float* b1    = (const float*)d_in[6];
    const float* Wl2   = (const float*)d_in[7];
    const float* Wr2   = (const float*)d_in[8];
    const float* att2  = (const float*)d_in[9];
    const float* Wres2 = (const float*)d_in[10];
    const float* b2    = (const float*)d_in[11];

    const int* srcp = ei;
    const int* dstp = ei + E_EDGES;

    // ---- workspace carve (~83 MB) ----
    size_t off = 0;
    char* base = (char*)d_ws;
    auto carve = [&](size_t bytes) -> void* {
        void* q = base + off;
        off += (bytes + 255) & ~(size_t)255;
        return q;
    };
    unsigned short* Wf = (unsigned short*)carve((size_t)6 * 16384 * 2);        // 192 KB
    unsigned short* A  = (unsigned short*)carve((size_t)N_NODES * CDIM * 2);   // 25.6 MB
    unsigned short* B  = (unsigned short*)carve((size_t)N_NODES * CDIM * 2);   // 25.6 MB
    unsigned short* X1 = (unsigned short*)carve((size_t)N_NODES * CDIM * 2);   // 25.6 MB
    int* cnt      = (int*)carve((size_t)N_NODES * 4);
    int* rowptr   = (int*)carve((size_t)(N_NODES + 1) * 4);
    int* cursor   = (int*)carve((size_t)N_NODES * 4);
    int* esrc     = (int*)carve((size_t)E_EDGES * 4);
    int* incl     = (int*)carve((size_t)N_NODES * 4);
    int* blockSums= (int*)carve((size_t)SCAN_NB * 4);
    (void)ws_size; (void)n_in; (void)in_sizes; (void)out_size;

    // ---- weight prep: all 6 mats, one launch ----
    pack_w_all<<<48, 256, 0, stream>>>(Wl1, Wr1, Wres1, Wl2, Wr2, Wres2, Wf);

    // ---- CSR build (dst-grouped), reused by both layers ----
    (void)hipMemsetAsync(cnt, 0, (size_t)N_NODES * 4, stream);
    hist_dst<<<(E_EDGES + 255) / 256, 256, 0, stream>>>(dstp, cnt, E_EDGES);
    scan_local<<<SCAN_NB, 256, 0, stream>>>(cnt, incl, blockSums, N_NODES);
    scan_sums<<<1, 128, 0, stream>>>(blockSums, SCAN_NB);
    add_offsets<<<(N_NODES + 255) / 256, 256, 0, stream>>>(incl, blockSums, cnt,
                                                           rowptr, cursor, N_NODES);
    scatter_edges<<<(E_EDGES + 255) / 256, 256, 0, stream>>>(srcp, dstp, cursor,
                                                             esrc, E_EDGES);

    float* R = (float*)d_out;   // residual accumulator for both layers (no aliasing with X)
    dim3 pgrid(3, NSTRIPS);
    int egrid = (N_NODES + 3) / 4;

    // layer 1: X=x (fp32, split) -> A,B,R=d_out; fused_edge -> X1 (bf16)
    proj1<true ><<<pgrid, 256, 0, stream>>>(x, Wf, b1, A, B, R, N_NODES);
    fused_edge<true ><<<egrid, 256, 0, stream>>>(rowptr, esrc, A, B, att1, R, X1, N_NODES);
    // layer 2: X=X1 (bf16, no split) -> A,B,R=d_out; fused_edge -> d_out (fp32, in-place rows)
    proj1<false><<<pgrid, 256, 0, stream>>>(X1, Wf + (size_t)3 * 16384, b2, A, B, R, N_NODES);
    fused_edge<false><<<egrid, 256, 0, stream>>>(rowptr, esrc, A, B, att2, R, d_out, N_NODES);
}

// Round 8
// 395.664 us; speedup vs baseline: 10.3783x; 1.0009x over previous
//
#include <hip/hip_runtime.h>
#include <math.h>

#define N_NODES 100000
#define CDIM 128
#define E_EDGES 500000
#define NEG_SLOPE 0.2f
#define SCAN_CHUNK 1024   // 256 threads x 4 items
#define SCAN_NB ((N_NODES + SCAN_CHUNK - 1) / SCAN_CHUNK)   // 98
#define NSTRIPS ((N_NODES + 63) / 64)                       // 1563

typedef __attribute__((ext_vector_type(8))) short short8;             // 8 bf16 (MFMA frag)
typedef __attribute__((ext_vector_type(8))) unsigned short ushort8;
typedef __attribute__((ext_vector_type(4))) unsigned short u16x4;
typedef __attribute__((ext_vector_type(4))) float f32x4;

static __device__ __forceinline__ float bf2f(unsigned short u) {
    unsigned int t = ((unsigned int)u) << 16;
    return __builtin_bit_cast(float, t);
}
static __device__ __forceinline__ unsigned short f2bf(float f) {
    unsigned int u = __builtin_bit_cast(unsigned int, f);
    unsigned int r = (u + 0x7FFFu + ((u >> 16) & 1u)) >> 16;   // RNE
    return (unsigned short)r;
}
static __device__ __forceinline__ int clampi(int v, int hi) {
    return v < 0 ? 0 : (v >= hi ? hi - 1 : v);
}
static __device__ __forceinline__ float lrelu(float v) {
    return v > 0.0f ? v : NEG_SLOPE * v;
}

// ---- pack all 6 fp32 128x128 W into MFMA-fragment-major bf16 ----
// chunk(kk,t): lane l (m=l&15,q=l>>4) owns W[kk*32+q*8+u][t*16+m], u=0..7.
__global__ __launch_bounds__(256)
void pack_w_all(const float* __restrict__ W0, const float* __restrict__ W1,
                const float* __restrict__ W2, const float* __restrict__ W3,
                const float* __restrict__ W4, const float* __restrict__ W5,
                unsigned short* __restrict__ Wf) {
    const float* Wp[6] = {W0, W1, W2, W3, W4, W5};
    int mi  = blockIdx.x >> 3;                       // 0..5 (block-uniform)
    int rem = ((blockIdx.x & 7) << 8) | threadIdx.x; // 0..2047
    const float* W = Wp[mi];
    int l = rem & 63, t = (rem >> 6) & 7, kk = rem >> 9;
    int m = l & 15, q = l >> 4;
    int j = t * 16 + m;
    int k0 = kk * 32 + q * 8;
    ushort8 o;
#pragma unroll
    for (int u = 0; u < 8; ++u) o[u] = f2bf(W[(k0 + u) * 128 + j]);
    *(ushort8*)(Wf + ((size_t)mi * 2048 + rem) * 8) = o;
}

// ---- fused 3-matrix projection: A=bf16(X@Wl), B=bf16(X@Wr), R=fp32(X@Wres+bias)
// a-operand = W frag, b-operand = X frag -> acc[t][r] = out[row0+lane%16][t*16+quad*4+r]
// (each lane owns 4 consecutive cols of ONE row -> wide stores). X read ONCE for all 3.
// XSPLIT: X fp32, hi/lo split (fp32-accurate). !XSPLIT: X bf16 (half the MFMAs).
// No LDS; W frags (96KB total) hit L1/L2. acc=96 VGPR -> ~3 waves/SIMD, 24-way MFMA ILP.
template <bool XSPLIT>
__global__ __launch_bounds__(256)
void projF(const void* __restrict__ Xv,
           const unsigned short* __restrict__ Wf,    // 3 mats, frag-major
           const float* __restrict__ bias,
           unsigned short* __restrict__ Aout,
           unsigned short* __restrict__ Bout,
           float* __restrict__ Rout, int n_rows) {
    const int wave = threadIdx.x >> 6;
    const int lane = threadIdx.x & 63;
    const int m = lane & 15, q = lane >> 4;
    const int row0 = blockIdx.x * 64 + wave * 16;
    const int xrow = row0 + m;                         // this lane's output row
    const int arow = xrow < n_rows ? xrow : n_rows - 1;

    f32x4 acc[3][8];
#pragma unroll
    for (int mi = 0; mi < 3; ++mi)
#pragma unroll
        for (int t = 0; t < 8; ++t) acc[mi][t] = (f32x4)0.0f;

#pragma unroll
    for (int kk = 0; kk < 4; ++kk) {
        short8 xh, xl_;
        if (XSPLIT) {
            const float* xp = (const float*)Xv + (size_t)arow * CDIM + kk * 32 + q * 8;
            f32x4 x0 = *(const f32x4*)xp;
            f32x4 x1 = *(const f32x4*)(xp + 4);
#pragma unroll
            for (int j = 0; j < 4; ++j) {
                unsigned short h0 = f2bf(x0[j]);
                xh[j] = (short)h0;
                xl_[j] = (short)f2bf(x0[j] - bf2f(h0));
                unsigned short h1 = f2bf(x1[j]);
                xh[4 + j] = (short)h1;
                xl_[4 + j] = (short)f2bf(x1[j] - bf2f(h1));
            }
        } else {
            xh = *(const short8*)((const unsigned short*)Xv +
                                  (size_t)arow * CDIM + kk * 32 + q * 8);
        }
#pragma unroll
        for (int t = 0; t < 8; ++t) {
            const size_t fo = ((size_t)(kk * 8 + t) * 64 + lane) * 8;
            short8 w0 = *(const short8*)(Wf + fo);
            short8 w1 = *(const short8*)(Wf + 16384 + fo);
            short8 w2 = *(const short8*)(Wf + 32768 + fo);
            acc[0][t] = __builtin_amdgcn_mfma_f32_16x16x32_bf16(w0, xh, acc[0][t], 0, 0, 0);
            acc[1][t] = __builtin_amdgcn_mfma_f32_16x16x32_bf16(w1, xh, acc[1][t], 0, 0, 0);
            acc[2][t] = __builtin_amdgcn_mfma_f32_16x16x32_bf16(w2, xh, acc[2][t], 0, 0, 0);
            if (XSPLIT) {
                acc[0][t] = __builtin_amdgcn_mfma_f32_16x16x32_bf16(w0, xl_, acc[0][t], 0, 0, 0);
                acc[1][t] = __builtin_amdgcn_mfma_f32_16x16x32_bf16(w1, xl_, acc[1][t], 0, 0, 0);
                acc[2][t] = __builtin_amdgcn_mfma_f32_16x16x32_bf16(w2, xl_, acc[2][t], 0, 0, 0);
            }
        }
    }

    if (xrow < n_rows) {
#pragma unroll
        for (int t = 0; t < 8; ++t) {
            u16x4 oa, ob;
#pragma unroll
            for (int r = 0; r < 4; ++r) { oa[r] = f2bf(acc[0][t][r]); ob[r] = f2bf(acc[1][t][r]); }
            *(u16x4*)(Aout + (size_t)xrow * CDIM + t * 16 + q * 4) = oa;
            *(u16x4*)(Bout + (size_t)xrow * CDIM + t * 16 + q * 4) = ob;
            f32x4 bv = *(const f32x4*)(bias + t * 16 + q * 4);
            *(f32x4*)(Rout + (size_t)xrow * CDIM + t * 16 + q * 4) = acc[2][t] + bv;
        }
    }
}

// ======================= CSR build (once per launch) =======================
__global__ __launch_bounds__(256)
void hist_dst(const int* __restrict__ dst, int* __restrict__ cnt, int n) {
    int e = blockIdx.x * 256 + threadIdx.x;
    if (e < n) atomicAdd(&cnt[clampi(dst[e], N_NODES)], 1);
}

__global__ __launch_bounds__(256)
void scan_local(const int* __restrict__ cnt, int* __restrict__ incl,
                int* __restrict__ blockSums, int n) {
    __shared__ int lds[256];
    int t = threadIdx.x;
    int base = blockIdx.x * SCAN_CHUNK + t * 4;
    int v[4], s = 0;
#pragma unroll
    for (int j = 0; j < 4; ++j) { v[j] = (base + j < n) ? cnt[base + j] : 0; s += v[j]; }
    lds[t] = s;
    __syncthreads();
    for (int off = 1; off < 256; off <<= 1) {
        int x = (t >= off) ? lds[t - off] : 0;
        __syncthreads();
        lds[t] += x;
        __syncthreads();
    }
    int run = lds[t] - s;
#pragma unroll
    for (int j = 0; j < 4; ++j) {
        run += v[j];
        if (base + j < n) incl[base + j] = run;
    }
    if (t == 255) blockSums[blockIdx.x] = lds[255];
}

__global__ __launch_bounds__(128)
void scan_sums(int* __restrict__ blockSums, int nb) {
    __shared__ int lds[128];
    int t = threadIdx.x;
    int v = (t < nb) ? blockSums[t] : 0;
    lds[t] = v;
    __syncthreads();
    for (int off = 1; off < 128; off <<= 1) {
        int x = (t >= off) ? lds[t - off] : 0;
        __syncthreads();
        lds[t] += x;
        __syncthreads();
    }
    if (t < nb) blockSums[t] = lds[t] - v;   // exclusive
}

__global__ __launch_bounds__(256)
void add_offsets(const int* __restrict__ incl, const int* __restrict__ blockSums,
                 const int* __restrict__ cnt, int* __restrict__ rowptr,
                 int* __restrict__ cursor, int n) {
    int i = blockIdx.x * 256 + threadIdx.x;
    if (i < n) {
        int v = incl[i] + blockSums[i / SCAN_CHUNK];
        rowptr[i + 1] = v;
        cursor[i] = v - cnt[i];
    }
    if (i == 0) rowptr[0] = 0;
}

__global__ __launch_bounds__(256)
void scatter_edges(const int* __restrict__ src, const int* __restrict__ dst,
                   int* __restrict__ cursor, int* __restrict__ esrc, int n) {
    int e = blockIdx.x * 256 + threadIdx.x;
    if (e < n) {
        int d = clampi(dst[e], N_NODES);
        int p = atomicAdd(&cursor[d], 1);
        esrc[p] = clampi(src[e], N_NODES);
    }
}

// ======================= fused edge phase =======================
// One wave per dst node; 2 ch/lane. den = sum exp(e); acc = sum exp(e)*xl[src].
// 4-edge unroll: four independent shuffle chains interleaved (latency hiding).
// Epilogue: Out[d] = relu(Rin[d] + acc/den).  BF16OUT: Out bf16 else fp32.
template <bool BF16OUT>
__global__ __launch_bounds__(256)
void fused_edge(const int* __restrict__ rowptr, const int* __restrict__ esrc,
                const unsigned short* __restrict__ A,
                const unsigned short* __restrict__ B,
                const float* __restrict__ att,
                const float* __restrict__ Rin, void* __restrict__ Outv, int n_nodes) {
    const int wave = threadIdx.x >> 6;
    const int lane = threadIdx.x & 63;
    const int d = blockIdx.x * 4 + wave;
    if (d >= n_nodes) return;
    const int c0 = lane * 2;

    unsigned int ub = *(const unsigned int*)(B + (size_t)d * CDIM + c0);
    const float b0 = bf2f((unsigned short)(ub & 0xffff));
    const float b1 = bf2f((unsigned short)(ub >> 16));
    const float at0 = att[c0];
    const float at1 = att[c0 + 1];

    float acc0 = 0.0f, acc1 = 0.0f, den = 0.0f;
    const int p0 = rowptr[d], p1 = rowptr[d + 1];
    int p = p0;
    for (; p + 4 <= p1; p += 4) {
        float a0[4], a1[4], e[4];
#pragma unroll
        for (int u = 0; u < 4; ++u) {
            int s = esrc[p + u];
            unsigned int ua = *(const unsigned int*)(A + (size_t)s * CDIM + c0);
            a0[u] = bf2f((unsigned short)(ua & 0xffff));
            a1[u] = bf2f((unsigned short)(ua >> 16));
            e[u] = lrelu(a0[u] + b0) * at0 + lrelu(a1[u] + b1) * at1;
        }
#pragma unroll
        for (int off = 32; off >= 1; off >>= 1) {
#pragma unroll
            for (int u = 0; u < 4; ++u) e[u] += __shfl_xor(e[u], off, 64);
        }
#pragma unroll
        for (int u = 0; u < 4; ++u) {
            float ee = __expf(fminf(e[u], 60.0f));   // |e| analytically << 60
            den  += ee;
            acc0 += ee * a0[u];
            acc1 += ee * a1[u];
        }
    }
    for (; p < p1; ++p) {
        int s = esrc[p];
        unsigned int ua = *(const unsigned int*)(A + (size_t)s * CDIM + c0);
        float a00 = bf2f((unsigned short)(ua & 0xffff));
        float a01 = bf2f((unsigned short)(ua >> 16));
        float e0 = lrelu(a00 + b0) * at0 + lrelu(a01 + b1) * at1;
#pragma unroll
        for (int off = 32; off >= 1; off >>= 1) e0 += __shfl_xor(e0, off, 64);
        float ee0 = __expf(fminf(e0, 60.0f));
        den  += ee0;
        acc0 += ee0 * a00;
        acc1 += ee0 * a01;
    }

    float inv = 1.0f / fmaxf(den, 1e-16f);
    const float* rp = Rin + (size_t)d * CDIM + c0;
    float2 r = *(const float2*)rp;
    float o0 = fmaxf(r.x + acc0 * inv, 0.0f);
    float o1 = fmaxf(r.y + acc1 * inv, 0.0f);
    if (BF16OUT) {
        unsigned int pk = (unsigned int)f2bf(o0) | ((unsigned int)f2bf(o1) << 16);
        *(unsigned int*)((unsigned short*)Outv + (size_t)d * CDIM + c0) = pk;
    } else {
        *(float2*)((float*)Outv + (size_t)d * CDIM + c0) = make_float2(o0, o1);
    }
}

extern "C" void kernel_launch(void* const* d_in, const int* in_sizes, int n_in,
                              void* d_out, int out_size, void* d_ws, size_t ws_size,
                              hipStream_t stream) {
    const float* x     = (const float*)d_in[0];
    const int*   ei    = (const int*)d_in[1];
    const float* Wl1   = (const float*)d_in[2];
    const float* Wr1   = (const float*)d_in[3];
    const float* att1  = (const float*)d_in[4];
    const float* Wres1 = (const float*)d_in[5];
    const float* b1    = (const float*)d_in[6];
    const float* Wl2   = (const float*)d_in[7];
    const float* Wr2   = (const float*)d_in[8];
    const float* att2  = (const float*)d_in[9];
    const float* Wres2 = (const float*)d_in[10];
    const float* b2    = (const float*)d_in[11];

    const int* srcp = ei;
    const int* dstp = ei + E_EDGES;

    // ---- workspace carve (~83 MB) ----
    size_t off = 0;
    char* base = (char*)d_ws;
    auto carve = [&](size_t bytes) -> void* {
        void* q = base + off;
        off += (bytes + 255) & ~(size_t)255;
        return q;
    };
    unsigned short* Wf = (unsigned short*)carve((size_t)6 * 16384 * 2);        // 192 KB
    unsigned short* A  = (unsigned short*)carve((size_t)N_NODES * CDIM * 2);   // 25.6 MB
    unsigned short* B  = (unsigned short*)carve((size_t)N_NODES * CDIM * 2);   // 25.6 MB
    unsigned short* X1 = (unsigned short*)carve((size_t)N_NODES * CDIM * 2);   // 25.6 MB
    int* cnt      = (int*)carve((size_t)N_NODES * 4);
    int* rowptr   = (int*)carve((size_t)(N_NODES + 1) * 4);
    int* cursor   = (int*)carve((size_t)N_NODES * 4);
    int* esrc     = (int*)carve((size_t)E_EDGES * 4);
    int* incl     = (int*)carve((size_t)N_NODES * 4);
    int* blockSums= (int*)carve((size_t)SCAN_NB * 4);
    (void)ws_size; (void)n_in; (void)in_sizes; (void)out_size;

    // ---- weight prep: all 6 mats, one launch ----
    pack_w_all<<<48, 256, 0, stream>>>(Wl1, Wr1, Wres1, Wl2, Wr2, Wres2, Wf);

    // ---- CSR build (dst-grouped), reused by both layers ----
    (void)hipMemsetAsync(cnt, 0, (size_t)N_NODES * 4, stream);
    hist_dst<<<(E_EDGES + 255) / 256, 256, 0, stream>>>(dstp, cnt, E_EDGES);
    scan_local<<<SCAN_NB, 256, 0, stream>>>(cnt, incl, blockSums, N_NODES);
    scan_sums<<<1, 128, 0, stream>>>(blockSums, SCAN_NB);
    add_offsets<<<(N_NODES + 255) / 256, 256, 0, stream>>>(incl, blockSums, cnt,
                                                           rowptr, cursor, N_NODES);
    scatter_edges<<<(E_EDGES + 255) / 256, 256, 0, stream>>>(srcp, dstp, cursor,
                                                             esrc, E_EDGES);

    float* R = (float*)d_out;   // residual accumulator for both layers (no aliasing with X)
    int egrid = (N_NODES + 3) / 4;

    // layer 1: X=x (fp32, split) -> A,B,R=d_out; fused_edge -> X1 (bf16)
    projF<true ><<<NSTRIPS, 256, 0, stream>>>(x, Wf, b1, A, B, R, N_NODES);
    fused_edge<true ><<<egrid, 256, 0, stream>>>(rowptr, esrc, A, B, att1, R, X1, N_NODES);
    // layer 2: X=X1 (bf16, no split) -> A,B,R=d_out; fused_edge -> d_out (fp32, in-place rows)
    projF<false><<<NSTRIPS, 256, 0, stream>>>(X1, Wf + (size_t)3 * 16384, b2, A, B, R, N_NODES);
    fused_edge<false><<<egrid, 256, 0, stream>>>(rowptr, esrc, A, B, att2, R, d_out, N_NODES);
}